// Round 27
// baseline (46.366 us; speedup 1.0000x reference)
//
#include <hip/hip_runtime.h>

#define IND 256
#define KC  32

typedef float v4f __attribute__((ext_vector_type(4)));   // native clang vector:
// __builtin_nontemporal_store requires scalar or native-vector types (not
// HIP_vector_type structs) -- this was R26's compile failure.

__global__ __launch_bounds__(256, 4)
void FeatureEncodingLayer_30374008718005_kernel(
        const float* __restrict__ X,      // [1024][256]
        const float* __restrict__ W,      // [4096][256]
        const float* __restrict__ bias,   // [4096]
        float* __restrict__ outf)         // [1024][4][4][2048] float32 = Re(kron)
{
    // Pair-interleaved, XOR-swizzled W tile (verified R17/R20):
    // word (kp, u, k&1) at Ws[buf][kp][(2u+(k&1)) ^ ((kp&7)<<2)], kp = k>>1.
    __shared__ float Ws[2][KC / 2][256];   // 32 KB

    const int tid  = threadIdx.x;
    const int lane = tid & 63;
    const int wid  = __builtin_amdgcn_readfirstlane(tid >> 6);  // wave 0..3

    // XCD-aware swizzle (bijective: 1024 = 8 XCD x 128).
    const int bid = ((int)blockIdx.x & 7) * 128 + ((int)blockIdx.x >> 3);

    const int ut = bid & 31;           // 32 unit tiles x 128 units
    const int bt = bid >> 5;           // 32 batch tiles x 32 batches
    const int b0 = bt * 32;
    const int u0 = ut * 128;
    const int p0 = ut * 64;

    const int q  = tid & 7;            // k-quad: local k = 4q..4q+3
    const int rq = tid >> 3;           // row subgroup 0..31

    const float* xc = X + (size_t)(b0 + 8 * wid) * IND;  // wave-uniform -> s_load

    float acc[8][2];
#pragma unroll
    for (int i = 0; i < 8; ++i) { acc[i][0] = 0.f; acc[i][1] = 0.f; }

    float4 pf[4];
#define STAGE_LOAD(c) do {                                                     \
    _Pragma("unroll")                                                          \
    for (int j = 0; j < 4; ++j)                                                \
        pf[j] = *reinterpret_cast<const float4*>(                              \
            W + (size_t)(u0 + rq + 32 * j) * IND + (c) * KC + q * 4);          \
    } while (0)

#define STAGE_WRITE(buf) do {                                                  \
    const int kp0 = 2 * q, kp1 = 2 * q + 1;                                    \
    const int sw0 = (kp0 & 7) << 2, sw1 = (kp1 & 7) << 2;                      \
    _Pragma("unroll")                                                          \
    for (int j = 0; j < 4; ++j) {                                              \
        const int u2 = 2 * (rq + 32 * j);                                      \
        *reinterpret_cast<float2*>(&Ws[buf][kp0][u2 ^ sw0]) =                  \
            make_float2(pf[j].x, pf[j].y);                                     \
        *reinterpret_cast<float2*>(&Ws[buf][kp1][u2 ^ sw1]) =                  \
            make_float2(pf[j].z, pf[j].w);                                     \
    }                                                                          \
    } while (0)

    // LDS-only barrier: global loads/stores stay in flight across it.
#define LDS_BARRIER() do {                                                     \
    asm volatile("s_waitcnt lgkmcnt(0)" ::: "memory");                         \
    __builtin_amdgcn_s_barrier();                                              \
    } while (0)

    STAGE_LOAD(0);
    STAGE_WRITE(0);
    LDS_BARRIER();

    for (int c = 0; c < IND / KC; ++c) {
        const int cur = c & 1;
        if (c < IND / KC - 1) STAGE_LOAD(c + 1);   // prefetch (no wait yet)

        // compute: per kp, 1 conflict-free ds_read_b128 + 32 FMA
#pragma unroll
        for (int kp = 0; kp < KC / 2; ++kp) {
            const int sw = (kp & 7) << 2;
            const float4 wq = *reinterpret_cast<const float4*>(
                &Ws[cur][kp][(4 * lane) ^ sw]);
            const int kg = c * KC + 2 * kp;
#pragma unroll
            for (int i = 0; i < 8; ++i) {
                const float x0 = xc[i * IND + kg];      // wave-uniform s_load
                const float x1 = xc[i * IND + kg + 1];
                acc[i][0] = fmaf(x0, wq.x, acc[i][0]);
                acc[i][0] = fmaf(x1, wq.y, acc[i][0]);
                acc[i][1] = fmaf(x0, wq.z, acc[i][1]);
                acc[i][1] = fmaf(x1, wq.w, acc[i][1]);
            }
        }
        if (c < IND / KC - 1) {
            STAGE_WRITE(cur ^ 1);                  // vmcnt wait: only its loads
            LDS_BARRIER();
        }
    }
#undef STAGE_LOAD
#undef STAGE_WRITE
#undef LDS_BARRIER

    // ==== epilogue: wave-local LDS transpose -> dwordx4 (nt) stores ====
    // Last chunk (c=7) read Ws[1]; Ws[0] (floats 0..4095) is dead -> each wave
    // takes a private 512-float slice. No cross-wave sharing => no barrier,
    // only wave-local lgkmcnt waits.
    // Scratch layout: T[s*64 + (pair ^ (s<<2))], s = nonzero-slot 0..7.
    float* T = &Ws[0][0][0] + wid * 512;
    const float2 bv = *reinterpret_cast<const float2*>(bias + u0 + 2 * lane);
    const int t16 = lane & 15;         // quad index: pairs 4*t16..4*t16+3
    const int rg  = lane >> 4;         // slot subgroup 0..3

#pragma unroll
    for (int i = 0; i < 8; ++i) {
        const int b = b0 + 8 * wid + i;
        const float tA = acc[i][0] + bv.x;
        const float tB = acc[i][1] + bv.y;
        float sA, cA, sB, cB;
        __sincosf(tA, &sA, &cA);
        __sincosf(tB, &sB, &cB);
        const float ca = 0.5f * (1.f + cA);   // cos^2(tA/2)
        const float sa = 0.5f * (1.f - cA);   // sin^2(tA/2)
        const float cb = 0.5f * (1.f + cB);
        const float sb = 0.5f * (1.f - cB);
        const float oo = 0.25f * sA * sB;     // sin(tA)/2 * sin(tB)/2

        // nonzero values for slots s=0..7 (rc {0,3,5,6,9,10,12,15})
        T[0 * 64 + (lane ^  0)] =  ca * cb;
        T[1 * 64 + (lane ^  4)] = -oo;
        T[2 * 64 + (lane ^  8)] =  ca * sb;
        T[3 * 64 + (lane ^ 12)] =  oo;
        T[4 * 64 + (lane ^ 16)] =  oo;
        T[5 * 64 + (lane ^ 20)] =  sa * cb;
        T[6 * 64 + (lane ^ 24)] = -oo;
        T[7 * 64 + (lane ^ 28)] =  sa * sb;

        asm volatile("s_waitcnt lgkmcnt(0)" ::: "memory");  // wave-local W->R

        float* bp = outf + (size_t)b * 32768 + p0 + 4 * t16;
#pragma unroll
        for (int rd = 0; rd < 2; ++rd) {
            const int s = 4 * rd + rg;
            const v4f vv = *reinterpret_cast<const v4f*>(
                &T[s * 64 + ((4 * t16) ^ (s << 2))]);
            const int rcn = (int)((0xFCA96530u >> (4 * s)) & 0xFu);
            const int rcz = (int)((0xEDB87421u >> (4 * s)) & 0xFu);
            const v4f zz = {0.f, 0.f, 0.f, 0.f};
            __builtin_nontemporal_store(vv,
                reinterpret_cast<v4f*>(bp + (size_t)rcn * 2048));
            __builtin_nontemporal_store(zz,
                reinterpret_cast<v4f*>(bp + (size_t)rcz * 2048));
        }
        asm volatile("s_waitcnt lgkmcnt(0)" ::: "memory");  // reads done before
                                                            // next batch reuses T
    }
}

extern "C" void kernel_launch(void* const* d_in, const int* in_sizes, int n_in,
                              void* d_out, int out_size, void* d_ws, size_t ws_size,
                              hipStream_t stream) {
    const float* X  = (const float*)d_in[0];
    const float* W  = (const float*)d_in[1];
    const float* bv = (const float*)d_in[2];

    // Champion shape: 1024 blocks, 256 threads, 4 blocks/CU.
    FeatureEncodingLayer_30374008718005_kernel<<<dim3(1024), dim3(256), 0, stream>>>(
        X, W, bv, (float*)d_out);
}